// Round 5
// baseline (3948.774 us; speedup 1.0000x reference)
//
#include <hip/hip_runtime.h>
#include <hip/hip_bf16.h>
#include <hip/hip_cooperative_groups.h>
#include <cstddef>
#include <cstdint>

namespace cg = cooperative_groups;

#define DD 2048
#define NRW 256
#define NCHUNK 16
#define CSZ 128
#define SCDP 4096.0f
#define NSTEP 16

typedef _Float16 h16;
typedef __attribute__((ext_vector_type(8))) _Float16 f16x8;
typedef __attribute__((ext_vector_type(4))) _Float16 f16x4;
typedef __attribute__((ext_vector_type(4))) float f32x4;

__device__ __forceinline__ float sigm(float v){ return 1.f/(1.f+__expf(-v)); }
__device__ __forceinline__ int xrow(int r, int t){ return (r>>7)*2048 + t*CSZ + (r&127); }
__device__ __forceinline__ f32x4 mfma16(f16x8 a, f16x8 b, f32x4 c){
  return __builtin_amdgcn_mfma_f32_16x16x32_f16(a, b, c, 0, 0, 0);
}

#define SBAR() do{ __builtin_amdgcn_sched_barrier(0); __builtin_amdgcn_s_barrier(); __builtin_amdgcn_sched_barrier(0); }while(0)
#define VMCNT(n) asm volatile("s_waitcnt vmcnt(" #n ")" ::: "memory")

__device__ __forceinline__ void gload16(const h16* g, h16* l){
  __builtin_amdgcn_global_load_lds((const __attribute__((address_space(1))) void*)g,
                                   (__attribute__((address_space(3))) void*)l, 16, 0, 0);
}

union SMem {
  struct { h16 As[3][32][128]; h16 Bs[3][64][128]; h16 Tb[64][40]; } rg;  // 78848 B
  struct { h16 As[64][256];    h16 Bs[64][256];    h16 Tb[64][72]; } up;  // 74752 B
};

struct ScanArgs {
  const h16* xh; const h16* xT;
  h16* W0h; h16* W1h; h16* W1Th;
  h16* ds; h16* hb; h16* hT; h16* dpb; h16* dpT; h16* dzT; h16* h2b;
  float* b0c; float* b1c;
  const float* x; const float* scal; float* out;
};

// ---------------------------------------------------------------------------
// Row GEMM phase (validated round-3 body): C[r,j]=sum_k A[r,k]*Bm[j,k](+bias)
// 256 tiles of 32(M)x64(N), BK=128, 3-buffer gload_lds pipeline.
// ---------------------------------------------------------------------------
template<int MODE>
__device__ void rg_phase(SMem& sm, int bid,
    const h16* __restrict__ A, const h16* __restrict__ Bm,
    const float* __restrict__ bias,
    const float* __restrict__ x, int t,
    const h16* __restrict__ dsin, h16* __restrict__ dsout,
    float* __restrict__ ofp, h16* __restrict__ ob, h16* __restrict__ obT)
{
  const int tid = threadIdx.x;
  const int j0 = (bid & 31) * 64;
  const int r0 = (bid >> 5) * 32;
  const int wid = tid >> 6, lane = tid & 63;
  const int wm = wid >> 2, wn = wid & 3;
  const int lr_ = lane & 15, lk = lane >> 4;
  const int sl4 = lane >> 4, su = lane & 15;
  const int arow = wid*4 + sl4;
  const int brow1 = 32 + arow;
  const size_t aoff  = (size_t)(r0 + arow)*DD + (size_t)((su ^ (arow&7))*8);
  const size_t boff0 = (size_t)(j0 + arow)*DD + (size_t)((su ^ (arow&7))*8);
  const size_t boff1 = (size_t)(j0 + brow1)*DD + (size_t)((su ^ (brow1&7))*8);
  h16* const as_base = &sm.rg.As[0][0][0];
  h16* const bs_base = &sm.rg.Bs[0][0][0];

  auto STAGE = [&](int b, int s){
    const size_t k0 = (size_t)s*128;
    gload16(A  + aoff  + k0, as_base + b*4096 + wid*512);
    gload16(Bm + boff0 + k0, bs_base + b*8192 + wid*512);
    gload16(Bm + boff1 + k0, bs_base + b*8192 + (wid+8)*512);
  };

  const int ar = wm*16 + lr_;
  const int br = wn*16 + lr_;
  int aidx[4], bidx[4];
#pragma unroll
  for (int q=0;q<4;++q){
    aidx[q] = ar*128 + ((q*4+lk)^(ar&7))*8;
    bidx[q] = br*128 + ((q*4+lk)^(br&7))*8;
  }

  f32x4 acc = {0.f,0.f,0.f,0.f};
  STAGE(0,0); STAGE(1,1);
  for (int s = 0; s < NSTEP; ++s){
    if (s < NSTEP-2){ STAGE((s+2)%3, s+2); VMCNT(6); }
    else if (s == NSTEP-2){ VMCNT(3); }
    else { VMCNT(0); }
    SBAR();
    const int cur = s%3;
    f16x8 a[4], b[4];
#pragma unroll
    for (int q=0;q<4;++q){
      a[q] = *(const f16x8*)(as_base + cur*4096 + aidx[q]);
      b[q] = *(const f16x8*)(bs_base + cur*8192 + bidx[q]);
    }
#pragma unroll
    for (int q=0;q<4;++q) acc = mfma16(a[q], b[q], acc);
    SBAR();
  }

  const int gc = j0 + wn*16 + lr_;
  const float bv = (MODE != 2) ? bias[gc] : 0.f;
#pragma unroll
  for (int ii=0;ii<4;++ii){
    const int gr = r0 + wm*16 + lk*4 + ii;
    float v = acc[ii] + bv;
    if (MODE == 0){
      float sg = sigm(v);
      float hval = v*sg;
      dsout[(size_t)gr*DD + gc] = (h16)(sg*(1.f + v*(1.f - sg)));
      ob[(size_t)gr*DD + gc] = (h16)hval;
      sm.rg.Tb[wn*16 + lr_][wm*16 + lk*4 + ii] = (h16)hval;
    } else if (MODE == 1){
      float xv = x[(size_t)xrow(gr,t)*DD + gc];
      float dpv = (SCDP*2.f/524288.f)*(v - xv);
      ob[(size_t)gr*DD + gc] = (h16)dpv;
      sm.rg.Tb[wn*16 + lr_][wm*16 + lk*4 + ii] = (h16)dpv;
    } else if (MODE == 2){
      float dzv = v * (float)dsin[(size_t)gr*DD + gc];
      sm.rg.Tb[wn*16 + lr_][wm*16 + lk*4 + ii] = (h16)dzv;
    } else if (MODE == 3){
      float sg = sigm(v);
      ob[(size_t)gr*DD + gc] = (h16)(v*sg);
    } else {
      ofp[(size_t)xrow(gr,t)*DD + gc] = v;
    }
  }
  if (MODE == 0 || MODE == 1 || MODE == 2){
    __syncthreads();
    const int lrow = tid >> 3, c4 = (tid & 7)*4;
    *(f16x4*)&obT[(size_t)(j0+lrow)*NRW + r0 + c4] = *(const f16x4*)&sm.rg.Tb[lrow][c4];
  }
}

// ---------------------------------------------------------------------------
// Weight update phase: 2048 tiles (1024 W1 + 1024 W0) over 256 blocks, 8 jobs
// each. G[i,j]=sum_r A[i,r]*B[j,r]; W=fg*W-lrs*G. W1 jobs refresh W1Th.
// Blocks 248..255 additionally update biases.
// ---------------------------------------------------------------------------
__device__ void upd_phase(SMem& sm, int bid,
    const h16* __restrict__ dpT, const h16* __restrict__ hT,
    const h16* __restrict__ dzT, const h16* __restrict__ xT,
    h16* __restrict__ W0h, h16* __restrict__ W1h, h16* __restrict__ W1Th,
    float* __restrict__ b0c, float* __restrict__ b1c,
    float lrs, float fg)
{
  const int tid = threadIdx.x;
  const int wid = tid >> 6, lane = tid & 63;
  const int wm = wid >> 2, wn = wid & 3;      // 2(M) x 4(N) waves; wave tile 32x16
  const int lr_ = lane & 15, lk = lane >> 4;
  const int sunit = lane & 31;
  h16* const as_base = &sm.up.As[0][0];
  h16* const bs_base = &sm.up.Bs[0][0];

  for (int it = 0; it < 8; ++it){
    const int T = it*256 + bid;
    const bool isW1 = (T < 1024);
    const int TT = isW1 ? T : T - 1024;
    const int i0 = (TT >> 5) * 64;
    const int j0 = (TT & 31) * 64;
    const h16* Asrc = isW1 ? dpT : dzT;
    const h16* Bsrc = isW1 ? hT  : xT;
#pragma unroll
    for (int q=0; q<4; ++q){
      const int rl = wid*8 + q*2 + (lane>>5);
      const size_t so = (size_t)((sunit ^ (rl&7))*8);
      gload16(Asrc + (size_t)(i0+rl)*NRW + so, as_base + (wid*8+q*2)*256);
      gload16(Bsrc + (size_t)(j0+rl)*NRW + so, bs_base + (wid*8+q*2)*256);
    }
    VMCNT(0);
    SBAR();
    f32x4 acc0 = {0.f,0.f,0.f,0.f}, acc1 = {0.f,0.f,0.f,0.f};
    const int ra0 = wm*32 + lr_, ra1 = ra0 + 16, rb = wn*16 + lr_;
#pragma unroll
    for (int s=0; s<8; ++s){
      const int u = s*4 + lk;
      f16x8 b  = *(const f16x8*)(bs_base + rb*256  + ((u^(rb&7))*8));
      f16x8 a0 = *(const f16x8*)(as_base + ra0*256 + ((u^(ra0&7))*8));
      f16x8 a1 = *(const f16x8*)(as_base + ra1*256 + ((u^(ra1&7))*8));
      acc0 = mfma16(a0,b,acc0);
      acc1 = mfma16(a1,b,acc1);
    }
    h16* Wh = isW1 ? W1h : W0h;
#pragma unroll
    for (int f=0; f<2; ++f){
      const f32x4 acc = f ? acc1 : acc0;
      const int gi = i0 + wm*32 + f*16 + lk*4;
      const int gj = j0 + wn*16 + lr_;
#pragma unroll
      for (int ii=0; ii<4; ++ii){
        const size_t idx = (size_t)(gi+ii)*DD + gj;
        float wv = fg*(float)Wh[idx] - lrs*acc[ii];
        Wh[idx] = (h16)wv;
        if (isW1) sm.up.Tb[wn*16+lr_][wm*32+f*16+lk*4+ii] = (h16)wv;
      }
    }
    if (isW1){
      __syncthreads();
      const int lrow = tid >> 3, c8 = (tid & 7)*8;
      *(f16x8*)&W1Th[(size_t)(j0+lrow)*DD + i0 + c8] = *(const f16x8*)&sm.up.Tb[lrow][c8];
    }
    __syncthreads();
  }
  if (bid >= 248){
    const int j = (bid-248)*512 + tid;   // 0..4095
    const h16* src = (j < DD) ? &dpT[(size_t)j*NRW] : &dzT[(size_t)(j-DD)*NRW];
    float s = 0.f;
    const f16x8* p = (const f16x8*)src;
#pragma unroll 4
    for (int q = 0; q < 32; ++q){
      f16x8 v = p[q];
#pragma unroll
      for (int e = 0; e < 8; ++e) s += (float)v[e];
    }
    if (j < DD) b1c[j]    = fg*b1c[j]    - lrs*s;
    else        b0c[j-DD] = fg*b0c[j-DD] - lrs*s;
  }
}

// ---------------------------------------------------------------------------
// The cooperative scan: 16 chunks x {fwd1, pred, dz, update, fwd2, out}
// ---------------------------------------------------------------------------
__global__ __launch_bounds__(512) void scan_coop(ScanArgs a)
{
  __shared__ SMem sm;
  cg::grid_group grid = cg::this_grid();
  const int bid = blockIdx.x;
  for (int t = 0; t < NCHUNK; ++t){
    const h16* xh_t = a.xh + (size_t)t*524288;
    const h16* xT_t = a.xT + (size_t)t*524288;
    const float lrs = a.scal[2*t] * (1.f/SCDP);
    const float fgv = a.scal[2*t+1];
    // fwd1: z=x@W0^T+b0 -> ds(dsilu), h (row+T)
    rg_phase<0>(sm, bid, xh_t, a.W0h, a.b0c, nullptr, t, nullptr, a.ds, nullptr, a.hb, a.hT);
    grid.sync();
    // pred -> dp (scaled, row+T)
    rg_phase<1>(sm, bid, a.hb, a.W1h, a.b1c, a.x, t, nullptr, nullptr, nullptr, a.dpb, a.dpT);
    grid.sync();
    // dz = (dp@W1)*dsilu -> dzT
    rg_phase<2>(sm, bid, a.dpb, a.W1Th, a.b1c, nullptr, t, a.ds, nullptr, nullptr, nullptr, a.dzT);
    grid.sync();
    // weight + bias update
    upd_phase(sm, bid, a.dpT, a.hT, a.dzT, xT_t, a.W0h, a.W1h, a.W1Th, a.b0c, a.b1c, lrs, fgv);
    grid.sync();
    // fwd2 with updated weights -> h2
    rg_phase<3>(sm, bid, xh_t, a.W0h, a.b0c, nullptr, t, nullptr, nullptr, nullptr, a.h2b, nullptr);
    grid.sync();
    // out = h2@W1'^T + b1' -> d_out (no sync needed before next fwd1)
    rg_phase<4>(sm, bid, a.h2b, a.W1h, a.b1c, nullptr, t, nullptr, nullptr, a.out, nullptr, nullptr);
  }
}

// ---------------------------------------------------------------------------
// Upfront prep: x -> h16 (row + per-chunk transposed) + gate partial dots
// ---------------------------------------------------------------------------
__global__ __launch_bounds__(256) void prepx(const float* __restrict__ x,
    const float* __restrict__ lr_w, const float* __restrict__ fg_w,
    h16* __restrict__ xh, h16* __restrict__ xT,
    float* __restrict__ rowacc, float* __restrict__ fgacc)
{
  __shared__ __align__(16) h16 Tb[64][72];
  __shared__ float red[4];
  const int tid = threadIdx.x;
  const int t = blockIdx.z;
  const int j0 = blockIdx.x*64, r0 = blockIdx.y*64;
  h16* xh_t = xh + (size_t)t*524288;
  h16* xT_t = xT + (size_t)t*524288;
  const int c4 = (tid & 15)*4, g = tid >> 4;
  const float4 lw = *(const float4*)&lr_w[j0+c4];
  const float4 fw = *(const float4*)&fg_w[j0+c4];
  float sfall = 0.f;
  float slv[4];
#pragma unroll
  for (int i=0;i<4;++i){
    const int row = g + i*16;
    float4 xv = *(const float4*)&x[(size_t)xrow(r0+row, t)*DD + j0 + c4];
    f16x4 hv; hv[0]=(h16)xv.x; hv[1]=(h16)xv.y; hv[2]=(h16)xv.z; hv[3]=(h16)xv.w;
    *(f16x4*)&xh_t[(size_t)(r0+row)*DD + j0 + c4] = hv;
    Tb[c4+0][row]=hv[0]; Tb[c4+1][row]=hv[1]; Tb[c4+2][row]=hv[2]; Tb[c4+3][row]=hv[3];
    float sl = xv.x*lw.x + xv.y*lw.y + xv.z*lw.z + xv.w*lw.w;
    float sf = xv.x*fw.x + xv.y*fw.y + xv.z*fw.z + xv.w*fw.w;
#pragma unroll
    for (int m=1;m<16;m<<=1) sl += __shfl_xor(sl, m);
    slv[i] = sl;
    sfall += sf;
  }
#pragma unroll
  for (int m=1;m<64;m<<=1) sfall += __shfl_xor(sfall, m);
  if ((tid&63)==0) red[tid>>6] = sfall;
  __syncthreads();
  if ((tid&15)==0){
#pragma unroll
    for (int i=0;i<4;++i) atomicAdd(&rowacc[t*256 + r0 + g + i*16], slv[i]);
  }
  if (tid==0) atomicAdd(&fgacc[2*t + (blockIdx.y>>1)], red[0]+red[1]+red[2]+red[3]);
  const int lcol = tid >> 2, r16 = (tid & 3)*16;
  *(f16x8*)&xT_t[(size_t)(j0+lcol)*NRW + r0 + r16]   = *(const f16x8*)&Tb[lcol][r16];
  *(f16x8*)&xT_t[(size_t)(j0+lcol)*NRW + r0 + r16+8] = *(const f16x8*)&Tb[lcol][r16+8];
}

__global__ __launch_bounds__(256) void gates(
    const float* __restrict__ rowacc, const float* __restrict__ fgacc,
    const float* __restrict__ lr_b, const float* __restrict__ fg_b,
    float* __restrict__ scal)
{
  __shared__ float red[256];
  const int tid = threadIdx.x, t = blockIdx.x;
  red[tid] = sigm(rowacc[t*256+tid] + lr_b[0]);
  __syncthreads();
  for (int o=128;o>0;o>>=1){ if (tid<o) red[tid]+=red[tid+o]; __syncthreads(); }
  if (tid==0){
    scal[2*t]   = 0.01f * red[0] * (1.f/256.f);
    scal[2*t+1] = 0.5f*( sigm(fgacc[2*t]*(1.f/128.f) + fg_b[0])
                       + sigm(fgacc[2*t+1]*(1.f/128.f) + fg_b[0]) );
  }
}

__global__ __launch_bounds__(256) void init_w1(const float* __restrict__ Wc,
    h16* __restrict__ Wh, h16* __restrict__ WTh)
{
  __shared__ __align__(16) h16 Tb[64][72];
  const int tid = threadIdx.x;
  const int j0 = blockIdx.x*64, i0 = blockIdx.y*64;
  const int c4 = (tid & 15)*4, rbase = tid >> 4;
#pragma unroll
  for (int i=0;i<4;++i){
    int row = rbase + i*16;
    float4 wv = *(const float4*)&Wc[(size_t)(i0+row)*DD + j0 + c4];
    f16x4 hv; hv[0]=(h16)wv.x; hv[1]=(h16)wv.y; hv[2]=(h16)wv.z; hv[3]=(h16)wv.w;
    *(f16x4*)&Wh[(size_t)(i0+row)*DD + j0 + c4] = hv;
    Tb[c4+0][row]=hv[0]; Tb[c4+1][row]=hv[1]; Tb[c4+2][row]=hv[2]; Tb[c4+3][row]=hv[3];
  }
  __syncthreads();
  const int lrow = tid >> 2, c16 = (tid & 3)*16;
  *(f16x8*)&WTh[(size_t)(j0+lrow)*DD + i0 + c16]   = *(const f16x8*)&Tb[lrow][c16];
  *(f16x8*)&WTh[(size_t)(j0+lrow)*DD + i0 + c16+8] = *(const f16x8*)&Tb[lrow][c16+8];
}

__global__ void init_w0(const float* __restrict__ Wc, h16* __restrict__ Wh){
  size_t i = ((size_t)blockIdx.x*256 + threadIdx.x)*4;
  float4 wv = *(const float4*)&Wc[i];
  f16x4 hv; hv[0]=(h16)wv.x; hv[1]=(h16)wv.y; hv[2]=(h16)wv.z; hv[3]=(h16)wv.w;
  *(f16x4*)&Wh[i] = hv;
}

extern "C" void kernel_launch(void* const* d_in, const int* in_sizes, int n_in,
                              void* d_out, int out_size, void* d_ws, size_t ws_size,
                              hipStream_t stream)
{
  const float* x    = (const float*)d_in[0];
  const float* W0   = (const float*)d_in[1];
  const float* b0   = (const float*)d_in[2];
  const float* W1   = (const float*)d_in[3];
  const float* b1   = (const float*)d_in[4];
  const float* lr_w = (const float*)d_in[5];
  const float* lr_b = (const float*)d_in[6];
  const float* fg_w = (const float*)d_in[7];
  const float* fg_b = (const float*)d_in[8];
  float* out = (float*)d_out;

  char* ws = (char*)d_ws;
  size_t off = 0;
  auto alloc = [&](size_t bytes)->char*{ char* p = ws + off; off += (bytes + 255) & ~255ull; return p; };
  float* b0c    = (float*)alloc(2048*4);
  float* b1c    = (float*)alloc(2048*4);
  float* stats  = (float*)alloc((16*256 + 32 + 32)*4);
  float* rowacc = stats;            // [16][256]
  float* fgacc  = stats + 16*256;   // [16][2]
  float* scal   = stats + 16*256 + 32; // [16][2]
  h16* W0h  = (h16*)alloc(4194304*2);
  h16* W1h  = (h16*)alloc(4194304*2);
  h16* W1Th = (h16*)alloc(4194304*2);
  h16* xh   = (h16*)alloc((size_t)16*524288*2);
  h16* xT   = (h16*)alloc((size_t)16*524288*2);
  h16* ds   = (h16*)alloc(524288*2);
  h16* hb   = (h16*)alloc(524288*2);
  h16* hT   = (h16*)alloc(524288*2);
  h16* dpb  = (h16*)alloc(524288*2);
  h16* dpT  = (h16*)alloc(524288*2);
  h16* dzT  = (h16*)alloc(524288*2);
  h16* h2b  = (h16*)alloc(524288*2);

  hipMemcpyAsync(b0c, b0, 2048*sizeof(float), hipMemcpyDeviceToDevice, stream);
  hipMemcpyAsync(b1c, b1, 2048*sizeof(float), hipMemcpyDeviceToDevice, stream);
  hipMemsetAsync(stats, 0, (16*256 + 32)*4, stream);

  dim3 blk256(256);
  init_w0<<<4096, blk256, 0, stream>>>(W0, W0h);
  init_w1<<<dim3(32,32), blk256, 0, stream>>>(W1, W1h, W1Th);
  prepx<<<dim3(32,4,16), blk256, 0, stream>>>(x, lr_w, fg_w, xh, xT, rowacc, fgacc);
  gates<<<16, blk256, 0, stream>>>(rowacc, fgacc, lr_b, fg_b, scal);

  ScanArgs sa;
  sa.xh = xh; sa.xT = xT;
  sa.W0h = W0h; sa.W1h = W1h; sa.W1Th = W1Th;
  sa.ds = ds; sa.hb = hb; sa.hT = hT; sa.dpb = dpb; sa.dpT = dpT; sa.dzT = dzT; sa.h2b = h2b;
  sa.b0c = b0c; sa.b1c = b1c;
  sa.x = x; sa.scal = scal; sa.out = out;
  void* kargs[] = { (void*)&sa };
  hipLaunchCooperativeKernel((const void*)scan_coop, dim3(256), dim3(512), kargs, 0, stream);
}